// Round 7
// baseline (4168.143 us; speedup 1.0000x reference)
//
#include <hip/hip_runtime.h>
#include <hip/hip_fp16.h>

// Resubmission: round-6 bench failed at GPU acquisition (infra), kernel untested.

#define Bc 4
#define Tc 256
#define Nc 4096
#define Kc 64
#define DEGc 4
#define Lc (Tc - 1)
#define NNZc (Bc * Nc * DEGc)   // 65536 edges per time-row (all batches)
#define NNZb (Nc * DEGc)        // 16384 edges per (t,b)
#define TPB_EM 256
#define TPB_SC 1024
#define INV_N (1.0f / 4096.0f)

typedef unsigned int u32;

// ---------------- block reductions (256-thread version for em) ----------------
template <int NT>
__device__ __forceinline__ float blockSumT(float v, volatile float* red) {
#pragma unroll
  for (int o = 1; o < 64; o <<= 1) v += __shfl_xor(v, o, 64);
  __syncthreads();
  if ((threadIdx.x & 63) == 0) red[threadIdx.x >> 6] = v;
  __syncthreads();
  float s = 0.f;
#pragma unroll
  for (int k = 0; k < NT / 64; ++k) s += red[k];
  return s;
}
template <int NT>
__device__ __forceinline__ float blockMaxT(float v, volatile float* red) {
#pragma unroll
  for (int o = 1; o < 64; o <<= 1) v = fmaxf(v, __shfl_xor(v, o, 64));
  __syncthreads();
  if ((threadIdx.x & 63) == 0) red[threadIdx.x >> 6] = v;
  __syncthreads();
  float m = -INFINITY;
#pragma unroll
  for (int k = 0; k < NT / 64; ++k) m = fmaxf(m, red[k]);
  return m;
}

// emexp[r][n] = softmax(obs[r,:] @ W)[n]; one block per row r = b*T + t.
// Rows with t > duration[b]-1 are never read by the scan -> skip.
__global__ __launch_bounds__(TPB_EM) void em_kernel(const float* __restrict__ obs,
                                                    const float* __restrict__ W,
                                                    const int* __restrict__ duration,
                                                    float* __restrict__ emexp) {
  const int r = blockIdx.x, tid = threadIdx.x;
  const int b = r >> 8, t = r & 255;
  if (t > duration[b] - 1) return;
  __shared__ float o[Kc];
  __shared__ float red[8];
  if (tid < Kc) o[tid] = obs[(size_t)r * Kc + tid];
  __syncthreads();
  float4 acc[4];
#pragma unroll
  for (int gI = 0; gI < 4; ++gI) acc[gI] = make_float4(0.f, 0.f, 0.f, 0.f);
  const float4* W4 = (const float4*)W;
  for (int k = 0; k < Kc; ++k) {
    const float ov = o[k];
    const float4* wr = W4 + (size_t)k * (Nc / 4);
#pragma unroll
    for (int gI = 0; gI < 4; ++gI) {
      float4 w = wr[gI * 256 + tid];
      acc[gI].x = fmaf(ov, w.x, acc[gI].x);
      acc[gI].y = fmaf(ov, w.y, acc[gI].y);
      acc[gI].z = fmaf(ov, w.z, acc[gI].z);
      acc[gI].w = fmaf(ov, w.w, acc[gI].w);
    }
  }
  float m = -INFINITY;
#pragma unroll
  for (int gI = 0; gI < 4; ++gI)
    m = fmaxf(m, fmaxf(fmaxf(acc[gI].x, acc[gI].y), fmaxf(acc[gI].z, acc[gI].w)));
  m = blockMaxT<TPB_EM>(m, red);
  float s = 0.f;
#pragma unroll
  for (int gI = 0; gI < 4; ++gI)
    s += __expf(acc[gI].x - m) + __expf(acc[gI].y - m) + __expf(acc[gI].z - m) + __expf(acc[gI].w - m);
  s = blockSumT<TPB_EM>(s, red);
  const float lse = m + __logf(s);
  float4* em4 = (float4*)emexp;
#pragma unroll
  for (int gI = 0; gI < 4; ++gI) {
    float4 w = acc[gI];
    w.x = __expf(w.x - lse); w.y = __expf(w.y - lse);
    w.z = __expf(w.z - lse); w.w = __expf(w.w - lse);
    em4[(size_t)r * (Nc / 4) + gI * 256 + tid] = w;
  }
}

// ---------------- compact: 16B/edge -> 4B/edge {u16 tgt | f16 exp(lv) << 16} ----
__device__ __forceinline__ u32 packEdge(int tgt, float lv) {
  const unsigned short h = __half_as_ushort(__float2half_rn(__expf(lv)));
  return (u32)tgt | ((u32)h << 16);
}

// block = 1024 edges of one (row, b); 16 blocks per (row,b). Skips rows past t*.
__global__ __launch_bounds__(256) void compact_kernel(const int* __restrict__ duration,
                                                      const int* __restrict__ tidx,
                                                      const float* __restrict__ tlv,
                                                      u32* __restrict__ ce) {
  const int gb = blockIdx.x;
  const int chunk = gb & 15;
  const int rb = gb >> 4;          // row*Bc + b
  const int b = rb & 3;
  const int row = rb >> 2;         // edge row (step t = row+1)
  if (row > duration[b] - 2) return;   // only rows 0..tstar-1 are consumed
  const int e_local = (chunk << 10) | (threadIdx.x << 2);
  const size_t ge = (size_t)row * NNZc + (size_t)b * NNZb + (size_t)e_local;
  const int4* ip = (const int4*)tidx + ((ge * 3) >> 2);
  const int4 i0 = ip[0], i1 = ip[1], i2 = ip[2];
  const float4 lv = *((const float4*)tlv + (ge >> 2));
  uint4 o;
  o.x = packEdge(i0.z, lv.x);   // tgt positions within 3 int4s: [0].z,[1].y,[2].x,[2].w
  o.y = packEdge(i1.y, lv.y);
  o.z = packEdge(i2.x, lv.z);
  o.w = packEdge(i2.w, lv.w);
  *((uint4*)(ce + (size_t)rb * NNZb) + (e_local >> 2)) = o;
}

// ---------------- scan: ONE block per batch, whole recurrence in LDS ----------
__device__ __forceinline__ float wToF(u32 p) {
  return __half2float(__ushort_as_half((unsigned short)(p >> 16)));
}

// 1024-thread sum. NO entry sync (callers place syncA); has one internal sync.
__device__ __forceinline__ float bsum1024(float x, volatile float* red) {
#pragma unroll
  for (int o = 1; o < 64; o <<= 1) x += __shfl_xor(x, o, 64);
  if ((threadIdx.x & 63) == 0) red[threadIdx.x >> 6] = x;
  __syncthreads();   // syncB
  float s = 0.f;
#pragma unroll
  for (int k = 0; k < 16; ++k) s += red[k];
  return s;
}

// Thread tid owns nodes 4tid..4tid+3 (a values in registers) and their 16 edges.
// Per round: register self-edge + 12 LDS atomic scatters -> syncA -> gather own
// 4 nodes (ds_read_b128) + re-zero -> v = (y+self)*em_t -> S_t reduce -> rescale.
// Edge/em data 2-deep register-prefetched (ping-pong A/B, refilled mid-round).
#define ROUND(T, E0, E1, E2, E3, EMC)                                              \
  {                                                                                \
    const int t_ = (T);                                                            \
    float4 self;                                                                   \
    self.x = a.x * wToF(E0.x);                                                     \
    atomicAdd(&Y[E0.y & 4095u], a.x * wToF(E0.y));                                 \
    atomicAdd(&Y[E0.z & 4095u], a.x * wToF(E0.z));                                 \
    atomicAdd(&Y[E0.w & 4095u], a.x * wToF(E0.w));                                 \
    self.y = a.y * wToF(E1.x);                                                     \
    atomicAdd(&Y[E1.y & 4095u], a.y * wToF(E1.y));                                 \
    atomicAdd(&Y[E1.z & 4095u], a.y * wToF(E1.z));                                 \
    atomicAdd(&Y[E1.w & 4095u], a.y * wToF(E1.w));                                 \
    self.z = a.z * wToF(E2.x);                                                     \
    atomicAdd(&Y[E2.y & 4095u], a.z * wToF(E2.y));                                 \
    atomicAdd(&Y[E2.z & 4095u], a.z * wToF(E2.z));                                 \
    atomicAdd(&Y[E2.w & 4095u], a.z * wToF(E2.w));                                 \
    self.w = a.w * wToF(E3.x);                                                     \
    atomicAdd(&Y[E3.y & 4095u], a.w * wToF(E3.y));                                 \
    atomicAdd(&Y[E3.z & 4095u], a.w * wToF(E3.z));                                 \
    atomicAdd(&Y[E3.w & 4095u], a.w * wToF(E3.w));                                 \
    const float4 emu = EMC;                                                        \
    { /* refill this buffer for round t_+2 (clamped; overlaps LDS backlog) */      \
      int tr_ = t_ + 1; if (tr_ > Lc - 1) tr_ = Lc - 1;                            \
      const uint4* rp_ = (const uint4*)(ce + (size_t)(tr_ * Bc + b) * NNZb) + (tid << 2); \
      E0 = rp_[0]; E1 = rp_[1]; E2 = rp_[2]; E3 = rp_[3];                          \
      int er_ = t_ + 2; if (er_ > Tc - 1) er_ = Tc - 1;                            \
      EMC = em4[(size_t)(embase + er_) * (Nc >> 2) + tid];                         \
    }                                                                              \
    __syncthreads(); /* syncA: all scatters done, prev red reads done */           \
    float4 y = *(float4*)&Y[tid << 2];                                             \
    *(float4*)&Y[tid << 2] = make_float4(0.f, 0.f, 0.f, 0.f);                      \
    v.x = (y.x + self.x) * emu.x; v.y = (y.y + self.y) * emu.y;                    \
    v.z = (y.z + self.z) * emu.z; v.w = (y.w + self.w) * emu.w;                    \
    const float S_ = bsum1024(v.x + v.y + v.z + v.w, red);                         \
    logacc += __logf(S_);                                                          \
    const float iv_ = 1.0f / S_;                                                   \
    a.x = v.x * iv_; a.y = v.y * iv_; a.z = v.z * iv_; a.w = v.w * iv_;            \
  }

__global__ __launch_bounds__(TPB_SC, 4) void scan_kernel(const int* __restrict__ duration,
                                                         const u32* __restrict__ ce,
                                                         const float* __restrict__ emexp,
                                                         float* __restrict__ out) {
  const int b = blockIdx.x, tid = threadIdx.x;
  __shared__ float Y[Nc];
  __shared__ float red[16];
  const int tstar = duration[b] - 1;
  const float4* em4 = (const float4*)emexp;
  const int embase = b * Tc;

  *(float4*)&Y[tid << 2] = make_float4(0.f, 0.f, 0.f, 0.f);

  // t = 0: alpha_0 = em_0 / N ; s_0 = sum(alpha_0)
  const float4 em0 = em4[(size_t)embase * (Nc >> 2) + tid];
  float4 v = make_float4(em0.x * INV_N, em0.y * INV_N, em0.z * INV_N, em0.w * INV_N);
  const float S0 = bsum1024(v.x + v.y + v.z + v.w, red);  // internal sync also fences Y zeroing
  float logacc = __logf(S0);
  {
    const float iv = 1.0f / S0;
    v.x *= iv; v.y *= iv; v.z *= iv; v.w *= iv;
  }
  float4 a = v;

  // 2-deep prefetch: rounds 1 and 2
  uint4 EA0, EA1, EA2, EA3, EB0, EB1, EB2, EB3;
  float4 emA, emB;
  {
    const uint4* p = (const uint4*)(ce + (size_t)(0 * Bc + b) * NNZb) + (tid << 2);
    EA0 = p[0]; EA1 = p[1]; EA2 = p[2]; EA3 = p[3];
    const uint4* q = (const uint4*)(ce + (size_t)(1 * Bc + b) * NNZb) + (tid << 2);
    EB0 = q[0]; EB1 = q[1]; EB2 = q[2]; EB3 = q[3];
    emA = em4[(size_t)(embase + 1) * (Nc >> 2) + tid];
    emB = em4[(size_t)(embase + 2) * (Nc >> 2) + tid];
  }

  int t = 1;
  while (t <= tstar) {
    ROUND(t, EA0, EA1, EA2, EA3, emA);
    ++t;
    if (t > tstar) break;
    ROUND(t, EB0, EB1, EB2, EB3, emB);
    ++t;
  }

  if (tid == 0) out[b] = logacc;   // log P = sum_{tau<=t*} log s_tau
}

extern "C" void kernel_launch(void* const* d_in, const int* in_sizes, int n_in,
                              void* d_out, int out_size, void* d_ws, size_t ws_size,
                              hipStream_t stream) {
  const float* obs = (const float*)d_in[0];
  const float* W = (const float*)d_in[1];
  const int* duration = (const int*)d_in[2];
  const int* tidx = (const int*)d_in[3];
  const float* tlv = (const float*)d_in[4];
  float* out = (float*)d_out;

  float* emexp = (float*)d_ws;                              // B*T*N f32 = 16 MB
  u32* ce = (u32*)(emexp + (size_t)Bc * Tc * Nc);           // Lc*Bc*NNZb u32 = 67 MB

  em_kernel<<<dim3(Bc * Tc), dim3(TPB_EM), 0, stream>>>(obs, W, duration, emexp);
  compact_kernel<<<dim3(Lc * Bc * 16), dim3(256), 0, stream>>>(duration, tidx, tlv, ce);
  scan_kernel<<<dim3(Bc), dim3(TPB_SC), 0, stream>>>(duration, ce, emexp, out);
}

// Round 9
// 2019.828 us; speedup vs baseline: 2.0636x; 2.0636x over previous
//
#include <hip/hip_runtime.h>
#include <hip/hip_fp16.h>

// Resubmission: round-8 bench failed at GPU acquisition (infra), kernel untested.

#define Bc 4
#define Tc 256
#define Nc 4096
#define Kc 64
#define Lc (Tc - 1)
#define NNZb (Nc * 4)          // 16384 edges per (row,b)
#define NNZc (Bc * NNZb)       // 65536 edges per time-row
#define EROW 4104              // u16 stride for ends rows (4097 used, 8B multiple)
#define INV_N (1.0f / 4096.0f)

typedef unsigned int u32;
typedef unsigned short u16;

// ---------------- 256-thread reductions (em kernel) ----------------
template <int NT>
__device__ __forceinline__ float blockSumT(float v, volatile float* red) {
#pragma unroll
  for (int o = 1; o < 64; o <<= 1) v += __shfl_xor(v, o, 64);
  __syncthreads();
  if ((threadIdx.x & 63) == 0) red[threadIdx.x >> 6] = v;
  __syncthreads();
  float s = 0.f;
#pragma unroll
  for (int k = 0; k < NT / 64; ++k) s += red[k];
  return s;
}
template <int NT>
__device__ __forceinline__ float blockMaxT(float v, volatile float* red) {
#pragma unroll
  for (int o = 1; o < 64; o <<= 1) v = fmaxf(v, __shfl_xor(v, o, 64));
  __syncthreads();
  if ((threadIdx.x & 63) == 0) red[threadIdx.x >> 6] = v;
  __syncthreads();
  float m = -INFINITY;
#pragma unroll
  for (int k = 0; k < NT / 64; ++k) m = fmaxf(m, red[k]);
  return m;
}

// emexp[r][n] = softmax(obs[r,:] @ W)[n]; one block per 4 CONSECUTIVE rows of one
// batch (cuts the W re-read from 1 GB to 256 MB of L2/L3 traffic).
__global__ __launch_bounds__(256) void em_kernel(const float* __restrict__ obs,
                                                 const float* __restrict__ W,
                                                 const int* __restrict__ duration,
                                                 float* __restrict__ emexp) {
  const int blk = blockIdx.x, tid = threadIdx.x;
  const int b = blk >> 6;                 // 64 blocks per batch (T/4)
  const int t0 = (blk & 63) << 2;
  if (t0 > duration[b] - 1) return;
  const int rbase = b * Tc + t0;
  __shared__ float osh[4][Kc];
  __shared__ float red[8];
  osh[tid >> 6][tid & 63] = obs[(size_t)(rbase + (tid >> 6)) * Kc + (tid & 63)];
  __syncthreads();
  float4 acc[4][4];
#pragma unroll
  for (int r = 0; r < 4; ++r)
#pragma unroll
    for (int g = 0; g < 4; ++g) acc[r][g] = make_float4(0.f, 0.f, 0.f, 0.f);
  const float4* W4 = (const float4*)W;
  for (int k = 0; k < Kc; ++k) {
#pragma unroll
    for (int g = 0; g < 4; ++g) {
      const float4 w = W4[(size_t)k * (Nc / 4) + g * 256 + tid];
#pragma unroll
      for (int r = 0; r < 4; ++r) {
        const float ov = osh[r][k];
        acc[r][g].x = fmaf(ov, w.x, acc[r][g].x);
        acc[r][g].y = fmaf(ov, w.y, acc[r][g].y);
        acc[r][g].z = fmaf(ov, w.z, acc[r][g].z);
        acc[r][g].w = fmaf(ov, w.w, acc[r][g].w);
      }
    }
  }
  float4* em4 = (float4*)emexp;
#pragma unroll
  for (int r = 0; r < 4; ++r) {
    float m = -INFINITY;
#pragma unroll
    for (int g = 0; g < 4; ++g)
      m = fmaxf(m, fmaxf(fmaxf(acc[r][g].x, acc[r][g].y), fmaxf(acc[r][g].z, acc[r][g].w)));
    m = blockMaxT<256>(m, red);
    float s = 0.f;
#pragma unroll
    for (int g = 0; g < 4; ++g)
      s += __expf(acc[r][g].x - m) + __expf(acc[r][g].y - m) +
           __expf(acc[r][g].z - m) + __expf(acc[r][g].w - m);
    s = blockSumT<256>(s, red);
    const float lse = m + __logf(s);
#pragma unroll
    for (int g = 0; g < 4; ++g) {
      float4 w = acc[r][g];
      w.x = __expf(w.x - lse); w.y = __expf(w.y - lse);
      w.z = __expf(w.z - lse); w.w = __expf(w.w - lse);
      em4[(size_t)(rbase + r) * (Nc / 4) + g * 256 + tid] = w;
    }
  }
}

// ---------------- counting sort: edges of one (row,b) bucketed by TARGET -------
// ce[rb][pos] = {src u16 | f16 exp(lv) << 16}; ends[rb][1+d] = CSR end of dest d.
__global__ __launch_bounds__(1024) void sort_kernel(const int* __restrict__ duration,
                                                    const int* __restrict__ tidx,
                                                    const float* __restrict__ tlv,
                                                    u32* __restrict__ ce,
                                                    u16* __restrict__ ends) {
  const int rb = blockIdx.x;           // row * Bc + b
  const int b = rb & 3, row = rb >> 2;
  if (row > duration[b] - 2) return;   // only rows 0..tstar-1 are consumed
  const int tid = threadIdx.x;
  __shared__ u32 cnt[Nc];
  __shared__ u32 wred[16];
  *(uint4*)&cnt[tid << 2] = make_uint4(0, 0, 0, 0);
  __syncthreads();

  // load my 16 edges (12 int4 of triplets + 4 float4 of logvals)
  const size_t ebase = (size_t)row * NNZc + (size_t)b * NNZb + (size_t)(tid << 4);
  const int4* ip = (const int4*)tidx + ((ebase * 3) >> 2);
  int4 c[12];
#pragma unroll
  for (int i = 0; i < 12; ++i) c[i] = ip[i];
  const float4* lp = (const float4*)tlv + (ebase >> 2);
  float4 lv[4];
#pragma unroll
  for (int g = 0; g < 4; ++g) lv[g] = lp[g];
  u32 tg[16];
#pragma unroll
  for (int g = 0; g < 4; ++g) {
    tg[4 * g + 0] = (u32)c[3 * g + 0].z;  // tgt at [0].z,[1].y,[2].x,[2].w per 4-edge group
    tg[4 * g + 1] = (u32)c[3 * g + 1].y;
    tg[4 * g + 2] = (u32)c[3 * g + 2].x;
    tg[4 * g + 3] = (u32)c[3 * g + 2].w;
  }
  // histogram (LDS atomics; wall-time amortized across 1020 parallel blocks)
#pragma unroll
  for (int k = 0; k < 16; ++k) atomicAdd(&cnt[tg[k]], 1u);
  __syncthreads();

  // exclusive scan of cnt[4096]
  uint4 c4 = *(uint4*)&cnt[tid << 2];
  const u32 s = c4.x + c4.y + c4.z + c4.w;
  u32 sc = s;
#pragma unroll
  for (int o = 1; o < 64; o <<= 1) {
    u32 nv = __shfl_up(sc, o, 64);
    if ((tid & 63) >= o) sc += nv;
  }
  if ((tid & 63) == 63) wred[tid >> 6] = sc;
  __syncthreads();
  if (tid < 64) {
    u32 wv = (tid < 16) ? wred[tid] : 0;
#pragma unroll
    for (int o = 1; o < 16; o <<= 1) {
      u32 nv = __shfl_up(wv, o, 64);
      if (tid >= o) wv += nv;
    }
    if (tid < 16) wred[tid] = wv;
  }
  __syncthreads();
  const u32 base = sc - s + ((tid >> 6) ? wred[(tid >> 6) - 1] : 0u);
  cnt[(tid << 2) + 0] = base;
  cnt[(tid << 2) + 1] = base + c4.x;
  cnt[(tid << 2) + 2] = base + c4.x + c4.y;
  cnt[(tid << 2) + 3] = base + c4.x + c4.y + c4.z;
  __syncthreads();

  // placement (cursor bump + scattered 4B store into the 64KB row window)
  u32* ceRow = ce + (size_t)rb * NNZb;
#pragma unroll
  for (int g = 0; g < 4; ++g) {
    const u32 src = (u32)((tid << 2) + g);
    const float l0 = lv[g].x, l1 = lv[g].y, l2 = lv[g].z, l3 = lv[g].w;
    u32 pos;
    pos = atomicAdd(&cnt[tg[4 * g + 0]], 1u);
    ceRow[pos] = src | ((u32)__half_as_ushort(__float2half_rn(__expf(l0))) << 16);
    pos = atomicAdd(&cnt[tg[4 * g + 1]], 1u);
    ceRow[pos] = src | ((u32)__half_as_ushort(__float2half_rn(__expf(l1))) << 16);
    pos = atomicAdd(&cnt[tg[4 * g + 2]], 1u);
    ceRow[pos] = src | ((u32)__half_as_ushort(__float2half_rn(__expf(l2))) << 16);
    pos = atomicAdd(&cnt[tg[4 * g + 3]], 1u);
    ceRow[pos] = src | ((u32)__half_as_ushort(__float2half_rn(__expf(l3))) << 16);
  }
  __syncthreads();

  // publish CSR ends (cursors now equal bucket ends)
  u16* eRow = ends + (size_t)rb * EROW;
  if (tid == 0) eRow[0] = 0;
#pragma unroll
  for (int i = 0; i < 4; ++i) eRow[1 + (tid << 2) + i] = (u16)cnt[(tid << 2) + i];
}

// ---------------- scan: one block per batch, gather-only (NO atomics) ----------
// 1024-thread sum; no entry sync (callers order via surrounding barriers).
__device__ __forceinline__ float bsum1024(float x, volatile float* red) {
#pragma unroll
  for (int o = 1; o < 64; o <<= 1) x += __shfl_xor(x, o, 64);
  if ((threadIdx.x & 63) == 0) red[threadIdx.x >> 6] = x;
  __syncthreads();
  float s = 0.f;
#pragma unroll
  for (int k = 0; k < 16; ++k) s += red[k];
  return s;
}

__global__ __launch_bounds__(1024) void scan_kernel(const int* __restrict__ duration,
                                                    const u32* __restrict__ ce,
                                                    const u16* __restrict__ ends,
                                                    const float* __restrict__ emexp,
                                                    float* __restrict__ out) {
  const int b = blockIdx.x, tid = threadIdx.x;
  __shared__ float A[Nc];
  __shared__ float red[16];
  const int tstar = duration[b] - 1;
  const float4* em4 = (const float4*)emexp;
  const size_t embase = (size_t)b * Tc;

  // t = 0
  const float4 em0 = em4[embase * (Nc / 4) + tid];
  float4 v = make_float4(em0.x * INV_N, em0.y * INV_N, em0.z * INV_N, em0.w * INV_N);
  float S = bsum1024(v.x + v.y + v.z + v.w, red);
  float logacc = __logf(S);
  float iv = __frcp_rn(S);
  *(float4*)&A[tid << 2] = make_float4(v.x * iv, v.y * iv, v.z * iv, v.w * iv);

  // prefetch round 1 boundaries + emission
  uint2 pe = make_uint2(0, 0);
  u32 pe4 = 0;
  float4 pem = make_float4(0.f, 0.f, 0.f, 0.f);
  if (tstar >= 1) {
    const u16* er = ends + (size_t)b * EROW;      // rb = 0*4 + b
    pe = *(const uint2*)(er + (tid << 2));        // eRow[4t .. 4t+3]
    pe4 = er[(tid << 2) + 4];
    pem = em4[(embase + 1) * (Nc / 4) + tid];
  }
  __syncthreads();  // A visible to all

  for (int t = 1; t <= tstar; ++t) {
    const u32 b0 = pe.x & 0xFFFFu, b1 = pe.x >> 16;
    const u32 b2 = pe.y & 0xFFFFu, b3 = pe.y >> 16, b4 = pe4;
    const u32* ceRow = ce + (size_t)(((t - 1) << 2) + b) * NNZb;
    const float4 emt = pem;

    // prefetch next round (covers full round of latency)
    if (t < tstar) {
      const u16* er = ends + (size_t)((t << 2) + b) * EROW;
      pe = *(const uint2*)(er + (tid << 2));
      pe4 = er[(tid << 2) + 4];
      pem = em4[(embase + t + 1) * (Nc / 4) + tid];
    }

    // gather edges for my 4 destinations: span [b0, b4), 4-wide pipelined
    float y0 = 0.f, y1 = 0.f, y2 = 0.f, y3 = 0.f;
    const u32 n = b4 - b0;   // >= 4 (self-loops guarantee deg >= 1)
    u32 p0 = ceRow[b0], p1 = ceRow[b0 + 1], p2 = ceRow[b0 + 2], p3 = ceRow[b0 + 3];
    for (u32 j = 0; j < n; j += 4) {
      const u32 q0 = p0, q1 = p1, q2 = p2, q3 = p3;
      const u32 nj = b0 + j + 4;   // overreads ce row end by <=32B (padded)
      p0 = ceRow[nj]; p1 = ceRow[nj + 1]; p2 = ceRow[nj + 2]; p3 = ceRow[nj + 3];
#define PROC(Q, K)                                                                    \
      {                                                                               \
        const u32 idx = b0 + j + (K);                                                 \
        float f = __half2float(__ushort_as_half((u16)((Q) >> 16))) * A[(Q) & 0xFFFFu];\
        f = (idx < b4) ? f : 0.f;                                                     \
        y0 += (idx < b1) ? f : 0.f;                                                   \
        y1 += (idx >= b1 && idx < b2) ? f : 0.f;                                      \
        y2 += (idx >= b2 && idx < b3) ? f : 0.f;                                      \
        y3 += (idx >= b3) ? f : 0.f;                                                  \
      }
      PROC(q0, 0) PROC(q1, 1) PROC(q2, 2) PROC(q3, 3)
#undef PROC
    }

    v.x = y0 * emt.x; v.y = y1 * emt.y; v.z = y2 * emt.z; v.w = y3 * emt.w;
    const float S_ = bsum1024(v.x + v.y + v.z + v.w, red);  // syncB inside
    logacc += __logf(S_);
    const float iv_ = __frcp_rn(S_);
    *(float4*)&A[tid << 2] = make_float4(v.x * iv_, v.y * iv_, v.z * iv_, v.w * iv_);
    __syncthreads();  // syncC: new A ready for next round
  }

  if (tid == 0) out[b] = logacc;   // log P = sum_{tau<=t*} log s_tau
}

extern "C" void kernel_launch(void* const* d_in, const int* in_sizes, int n_in,
                              void* d_out, int out_size, void* d_ws, size_t ws_size,
                              hipStream_t stream) {
  const float* obs = (const float*)d_in[0];
  const float* W = (const float*)d_in[1];
  const int* duration = (const int*)d_in[2];
  const int* tidx = (const int*)d_in[3];
  const float* tlv = (const float*)d_in[4];
  float* out = (float*)d_out;

  float* emexp = (float*)d_ws;                                   // 16.8 MB
  u32* ce = (u32*)(emexp + (size_t)Bc * Tc * Nc);                // 66.8 MB (+pad)
  u16* ends = (u16*)(ce + (size_t)Lc * Bc * NNZb + 32);          // 8.4 MB

  em_kernel<<<dim3(Bc * (Tc / 4)), dim3(256), 0, stream>>>(obs, W, duration, emexp);
  sort_kernel<<<dim3(Lc * Bc), dim3(1024), 0, stream>>>(duration, tidx, tlv, ce, ends);
  scan_kernel<<<dim3(Bc), dim3(1024), 0, stream>>>(duration, ce, ends, emexp, out);
}